// Round 6
// baseline (108.407 us; speedup 1.0000x reference)
//
#include <hip/hip_runtime.h>

#define N_TOT 8192
#define NS 4096
#define D 256                 // elements per row; fp8 => also bytes per row
#define NB 64                 // 8192/128 tiles per dim
#define NTRI (NB*(NB+1)/2)    // 2080 upper-triangle tiles
#define HALF_B 32

typedef float f32x16 __attribute__((ext_vector_type(16)));
typedef float f32x2 __attribute__((ext_vector_type(2)));
typedef int i32x4 __attribute__((ext_vector_type(4)));
typedef int i32x8 __attribute__((ext_vector_type(8)));

__device__ __forceinline__ void gload16(const void* g, void* l) {
  __builtin_amdgcn_global_load_lds(
      (const __attribute__((address_space(1))) unsigned int*)g,
      (__attribute__((address_space(3))) unsigned int*)l,
      16, 0, 0);
}

// ---- K1: fp8 convert + row sq-norms + column sums, fused bandwidth finalize.
// Fence-free last-block pattern: all cross-block data moves via device-scope
// f64 atomicAdds (coherence-point ops); the counter increment is ordered after
// the data atomics by per-wave s_waitcnt vmcnt(0) + __syncthreads.
// 256 blocks x 512 threads (2 blocks/CU -> 2x latency hiding vs 256-thr).
__global__ __launch_bounds__(512) void k_prep(
    const float* __restrict__ src, const float* __restrict__ tgt,
    unsigned char* __restrict__ Xb, float* __restrict__ sqv,
    double* __restrict__ colsum, double* __restrict__ wsqacc,
    unsigned* __restrict__ cnt1, float* __restrict__ coef) {
  __shared__ float colacc[256];
  __shared__ float wred[8];
  __shared__ double red[256];
  __shared__ int isl;
  int t = threadIdx.x, l = t & 63, w = t >> 6;   // 8 waves
  if (t < 256) colacc[t] = 0.f;
  __syncthreads();
  int base = blockIdx.x * 32;
  float c0 = 0.f, c1 = 0.f, c2 = 0.f, c3 = 0.f;
  float wsq = 0.f;
  #pragma unroll
  for (int r = 0; r < 4; ++r) {
    int row = base + w * 4 + r;
    const float* p = (row < NS) ? (src + (size_t)row * D) : (tgt + (size_t)(row - NS) * D);
    float4 v = ((const float4*)p)[l];
    int pk = __builtin_amdgcn_cvt_pk_fp8_f32(v.x, v.y, 0, false);   // bytes 0,1
    pk = __builtin_amdgcn_cvt_pk_fp8_f32(v.z, v.w, pk, true);       // bytes 2,3
    ((int*)(Xb + (size_t)row * D))[l] = pk;                         // 4 B/lane coalesced
    c0 += v.x; c1 += v.y; c2 += v.z; c3 += v.w;
    float s = fmaf(v.x, v.x, fmaf(v.y, v.y, fmaf(v.z, v.z, v.w * v.w)));
    for (int o = 32; o > 0; o >>= 1) s += __shfl_down(s, o, 64);
    if (l == 0) { sqv[row] = s; wsq += s; }
  }
  atomicAdd(&colacc[4 * l + 0], c0);
  atomicAdd(&colacc[4 * l + 1], c1);
  atomicAdd(&colacc[4 * l + 2], c2);
  atomicAdd(&colacc[4 * l + 3], c3);
  if (l == 0) wred[w] = wsq;
  __syncthreads();
  if (t < 256) atomicAdd(&colsum[t], (double)colacc[t]);
  if (t == 0) {
    float ws8 = ((wred[0] + wred[1]) + (wred[2] + wred[3])) +
                ((wred[4] + wred[5]) + (wred[6] + wred[7]));
    atomicAdd(wsqacc, (double)ws8);
  }
  asm volatile("s_waitcnt vmcnt(0)" ::: "memory");   // each wave drains its atomics
  __syncthreads();
  if (t == 0) isl = (atomicAdd(cnt1, 1u) == 255u) ? 1 : 0;
  __syncthreads();
  if (isl) {
    // all 255 other blocks' atomics are at the coherence point; read atomically
    if (t < 256) {
      double d = atomicAdd(&colsum[t], 0.0);
      red[t] = d * d;
    }
    __syncthreads();
    for (int s = 128; s > 0; s >>= 1) {
      if (t < s) red[t] += red[t + s];
      __syncthreads();
    }
    if (t == 0) {
      double msq = red[0];                          // ||sum x||^2
      double Sv = atomicAdd(wsqacc, 0.0);           // sum ||x||^2
      double n = (double)N_TOT;
      double sumL2 = 2.0 * n * Sv - 2.0 * msq;
      double bw = sumL2 / (n * n - n) / 4.0;        // / KERNEL_MUL**(KERNEL_NUM//2)
      double c4 = 1.0 / (bw * 16.0 + 1e-6);         // widest kernel (k=4)
      coef[0] = (float)(c4 * 1.4426950408889634);   // * log2(e) for exp2
    }
  }
}

// ---- K3: 128x128 upper-tri tiles, MX-scaled fp8 32x32x64 MFMA (unit scales) ----
// r0-exact compute core (best measured). Fused final reduction via fence-free
// f64 bin atomics + counter; last block reduces 32 bins and writes out.
__global__ __launch_bounds__(256) void k_main(
    const unsigned char* __restrict__ Xb, const float* __restrict__ sqv,
    const float* __restrict__ coef, double* __restrict__ gbins,
    unsigned* __restrict__ cnt2, float* __restrict__ out) {
  // triangular decode: block b -> (bi, bj), bi <= bj
  int b = blockIdx.x;
  int bi = (int)((2.f * NB + 1.f - sqrtf((float)((2 * NB + 1) * (2 * NB + 1) - 8 * b))) * 0.5f);
  if (bi < 0) bi = 0;
  if (bi > NB - 1) bi = NB - 1;
  while ((bi + 1) * (2 * NB - bi) / 2 <= b) ++bi;
  while (bi * (2 * NB - bi + 1) / 2 > b) --bi;
  int bj = bi + (b - bi * (2 * NB - bi + 1) / 2);

  __shared__ unsigned char ldsA[128 * 64];   // 8 KB  [row][64B stage-slice]
  __shared__ unsigned char ldsB[128 * 64];   // 8 KB
  __shared__ float sqA[128], sqB[128];
  __shared__ float redw[4];
  __shared__ int islast;

  int t = threadIdx.x, l = t & 63, w = t >> 6;
  int lr = l & 31, half = l >> 5;
  int waveRow = w >> 1, waveCol = w & 1;

  if (t < 128) sqA[t] = sqv[bi * 128 + t];
  else         sqB[t - 128] = sqv[bj * 128 + (t - 128)];
  float A4 = coef[0];

  const unsigned char* arow = Xb + (size_t)bi * 128 * D;
  const unsigned char* brow = Xb + (size_t)bj * 128 * D;

  f32x16 acc[2][2] = {};
  int cLo = 2 * half, cHi = 2 * half + 1;   // lane's logical 16B chunks

  for (int ko = 0; ko < 4; ++ko) {
    if (ko) __syncthreads();
    int kOff = ko * 64;                     // byte offset in row
    #pragma unroll
    for (int p = 0; p < 2; ++p) {           // 512 16B segs per matrix
      int seg = p * 256 + t;
      int row = seg >> 2;
      int kb = (seg & 3) ^ (row & 3) ^ ((row >> 2) & 3);
      int goff = row * D + kOff + kb * 16;
      gload16(arow + goff, &ldsA[(p * 256 + w * 64) * 16]);
      gload16(brow + goff, &ldsB[(p * 256 + w * 64) * 16]);
    }
    __syncthreads();
    i32x8 aF[2];
    #pragma unroll
    for (int rb = 0; rb < 2; ++rb) {
      int rowA = waveRow * 64 + rb * 32 + lr;
      int sw = (rowA & 3) ^ ((rowA >> 2) & 3);
      i32x4 lo = *(const i32x4*)&ldsA[rowA * 64 + (cLo ^ sw) * 16];
      i32x4 hi = *(const i32x4*)&ldsA[rowA * 64 + (cHi ^ sw) * 16];
      aF[rb] = (i32x8){lo.x, lo.y, lo.z, lo.w, hi.x, hi.y, hi.z, hi.w};
    }
    #pragma unroll
    for (int cb = 0; cb < 2; ++cb) {
      int rowB = waveCol * 64 + cb * 32 + lr;
      int sw = (rowB & 3) ^ ((rowB >> 2) & 3);
      i32x4 lo = *(const i32x4*)&ldsB[rowB * 64 + (cLo ^ sw) * 16];
      i32x4 hi = *(const i32x4*)&ldsB[rowB * 64 + (cHi ^ sw) * 16];
      i32x8 bF = (i32x8){lo.x, lo.y, lo.z, lo.w, hi.x, hi.y, hi.z, hi.w};
      #pragma unroll
      for (int rb = 0; rb < 2; ++rb)
        acc[rb][cb] = __builtin_amdgcn_mfma_scale_f32_32x32x64_f8f6f4(
            aF[rb], bF, acc[rb][cb], 0, 0, 0, 127, 0, 127);
    }
  }

  // Packed epilogue: tt = 2A4*dot - A4*sqi - A4*sqj ; e = exp2(tt)
  // sum5 = e+e^2+e^4+e^8+e^16 (exp-squaring; bw_k = bw*2^k exactly)
  float c2A4 = 2.f * A4, nA4 = -A4;
  f32x2 lsum2 = {0.f, 0.f};
  bool diag = (bi == bj);
  #pragma unroll
  for (int cb = 0; cb < 2; ++cb) {
    int jj = waveCol * 64 + cb * 32 + lr;
    float bjv = nA4 * sqB[jj];
    #pragma unroll
    for (int rb = 0; rb < 2; ++rb) {
      #pragma unroll
      for (int r = 0; r < 16; r += 2) {
        int ii = waveRow * 64 + rb * 32 + (r & 3) + 8 * (r >> 2) + 4 * half;
        f32x2 dot2 = {acc[rb][cb][r], acc[rb][cb][r + 1]};
        f32x2 sq2 = {sqA[ii], sqA[ii + 1]};
        f32x2 tt = c2A4 * dot2 + (nA4 * sq2 + bjv);
        f32x2 e;
        e.x = __builtin_amdgcn_exp2f(tt.x);
        e.y = __builtin_amdgcn_exp2f(tt.y);
        f32x2 e2 = e * e, e4 = e2 * e2, e8 = e4 * e4, e16 = e8 * e8;
        f32x2 kern = ((e + e2) + (e4 + e8)) + e16;
        if (diag) {                          // block-uniform branch
          if (ii == jj) kern.x = 0.f;
          if (ii + 1 == jj) kern.y = 0.f;
        }
        lsum2 += kern;
      }
    }
  }
  float lsum = lsum2.x + lsum2.y;
  for (int o = 32; o > 0; o >>= 1) lsum += __shfl_down(lsum, o, 64);
  if (l == 0) redw[w] = lsum;
  __syncthreads();
  if (t == 0) {
    float tot = (redw[0] + redw[1]) + (redw[2] + redw[3]);
    float wgt = diag ? 1.f : 2.f;                               // symmetry weight
    float sgn = ((bi < HALF_B) == (bj < HALF_B)) ? 1.f : -1.f;  // s_i * s_j
    atomicAdd(&gbins[b & 31], (double)(tot * wgt * sgn));
    asm volatile("s_waitcnt vmcnt(0)" ::: "memory");            // bin add at L3 first
    islast = (atomicAdd(cnt2, 1u) == (unsigned)(NTRI - 1)) ? 1 : 0;
  }
  __syncthreads();
  if (islast) {
    if (t < 32) {
      double d = atomicAdd(&gbins[t], 0.0);        // atomic read at coherence point
      for (int o = 16; o > 0; o >>= 1) d += __shfl_down(d, o, 32);
      if (t == 0) {
        double total = d + 5.0 * (double)N_TOT;    // diagonal: K_ii = 5, sign +1
        out[0] = (float)(total / ((double)NS * (double)NS));
      }
    }
  }
}

extern "C" void kernel_launch(void* const* d_in, const int* in_sizes, int n_in,
                              void* d_out, int out_size, void* d_ws, size_t ws_size,
                              hipStream_t stream) {
  const float* src = (const float*)d_in[0];
  const float* tgt = (const float*)d_in[1];
  float* out = (float*)d_out;
  char* ws = (char*)d_ws;
  unsigned char* Xb = (unsigned char*)ws;                  // 2 MB fp8 row-major
  float* sqv = (float*)(ws + (4u << 20));                  // 32 KB row sq-norms
  char* zr = ws + (4u << 20) + (64u << 10);                // zeroed accumulator region
  double* colsum  = (double*)zr;                           // 2048 B (256 f64)
  double* wsqacc  = (double*)(zr + 2048);                  // 8 B
  double* gbins   = (double*)(zr + 2056);                  // 256 B (32 f64)
  unsigned* cnt1  = (unsigned*)(zr + 2312);                // 4 B
  unsigned* cnt2  = (unsigned*)(zr + 2316);                // 4 B
  float* coef     = (float*)(zr + 2320);                   // 4 B

  hipMemsetAsync(zr, 0, 2560, stream);
  hipLaunchKernelGGL(k_prep, dim3(256), dim3(512), 0, stream,
                     src, tgt, Xb, sqv, colsum, wsqacc, cnt1, coef);
  hipLaunchKernelGGL(k_main, dim3(NTRI), dim3(256), 0, stream,
                     Xb, sqv, coef, gbins, cnt2, out);
}

// Round 7
// 100.204 us; speedup vs baseline: 1.0819x; 1.0819x over previous
//
#include <hip/hip_runtime.h>

#define N_TOT 8192
#define NS 4096
#define D 256                 // elements per row; fp8 => also bytes per row
#define NB2 32                // 8192/256 tiles per dim (k_main)
#define NTRI2 (NB2*(NB2+1)/2) // 528 upper-triangle 256x256 tiles
#define HALF_B2 16

typedef float f32x16 __attribute__((ext_vector_type(16)));
typedef float f32x2 __attribute__((ext_vector_type(2)));
typedef int i32x4 __attribute__((ext_vector_type(4)));
typedef int i32x8 __attribute__((ext_vector_type(8)));

__device__ __forceinline__ void gload16(const void* g, void* l) {
  __builtin_amdgcn_global_load_lds(
      (const __attribute__((address_space(1))) unsigned int*)g,
      (__attribute__((address_space(3))) unsigned int*)l,
      16, 0, 0);
}

// ---- K1: one pass: fp8 e4m3 convert + row sq-norms + per-block partials ----
// (r5 exact)
__global__ void k_prep(const float* __restrict__ src, const float* __restrict__ tgt,
                       unsigned char* __restrict__ Xb, float* __restrict__ sqv,
                       float* __restrict__ pm, float* __restrict__ wsqp) {
  __shared__ float colacc[256];
  __shared__ float wred[4];
  int t = threadIdx.x, l = t & 63, w = t >> 6;
  colacc[t] = 0.f;
  __syncthreads();
  int base = blockIdx.x * 32;
  float c0 = 0.f, c1 = 0.f, c2 = 0.f, c3 = 0.f;
  float wsq = 0.f;
  #pragma unroll
  for (int r = 0; r < 8; ++r) {
    int row = base + w * 8 + r;
    const float* p = (row < NS) ? (src + (size_t)row * D) : (tgt + (size_t)(row - NS) * D);
    float4 v = ((const float4*)p)[l];
    int pk = __builtin_amdgcn_cvt_pk_fp8_f32(v.x, v.y, 0, false);   // bytes 0,1
    pk = __builtin_amdgcn_cvt_pk_fp8_f32(v.z, v.w, pk, true);       // bytes 2,3
    ((int*)(Xb + (size_t)row * D))[l] = pk;                         // 4 B/lane coalesced
    c0 += v.x; c1 += v.y; c2 += v.z; c3 += v.w;
    float s = fmaf(v.x, v.x, fmaf(v.y, v.y, fmaf(v.z, v.z, v.w * v.w)));
    for (int o = 32; o > 0; o >>= 1) s += __shfl_down(s, o, 64);
    if (l == 0) { sqv[row] = s; wsq += s; }
  }
  atomicAdd(&colacc[4 * l + 0], c0);
  atomicAdd(&colacc[4 * l + 1], c1);
  atomicAdd(&colacc[4 * l + 2], c2);
  atomicAdd(&colacc[4 * l + 3], c3);
  if (l == 0) wred[w] = wsq;
  __syncthreads();
  pm[blockIdx.x * 256 + t] = colacc[t];
  if (t == 0) wsqp[blockIdx.x] = (wred[0] + wred[1]) + (wred[2] + wred[3]);
}

// ---- K2: reduce partials, finalize bandwidth in fp64 (r5 exact) ----
__global__ __launch_bounds__(1024) void k_bw(const float* __restrict__ pm,
                                             const float* __restrict__ wsqp,
                                             float* __restrict__ coef) {
  __shared__ float csh[1024];
  __shared__ double red[256];
  int t = threadIdx.x;
  int col = t & 255, q = t >> 8;          // q = 0..3: which 64-block slice
  float cs = 0.f;
  #pragma unroll
  for (int b = 0; b < 64; ++b) cs += pm[(q * 64 + b) * 256 + col];
  csh[t] = cs;
  __syncthreads();
  if (t < 256) {
    float c = (csh[t] + csh[t + 256]) + (csh[t + 512] + csh[t + 768]);
    red[t] = (double)c * (double)c;
  }
  __syncthreads();
  for (int s = 128; s > 0; s >>= 1) {
    if (t < s) red[t] += red[t + s];
    __syncthreads();
  }
  double msq = red[0];
  __syncthreads();
  if (t < 256) red[t] = (double)wsqp[t];
  __syncthreads();
  for (int s = 128; s > 0; s >>= 1) {
    if (t < s) red[t] += red[t + s];
    __syncthreads();
  }
  if (t == 0) {
    double Sv = red[0];
    double n = (double)N_TOT;
    double sumL2 = 2.0 * n * Sv - 2.0 * msq;
    double bw = sumL2 / (n * n - n) / 4.0;        // / KERNEL_MUL**(KERNEL_NUM//2)
    double c4 = 1.0 / (bw * 16.0 + 1e-6);         // widest kernel (k=4)
    coef[0] = (float)(c4 * 1.4426950408889634);   // * log2(e) for exp2
  }
}

// ---- K3: 256x256 upper-tri tiles, 1024 thr / 16 waves, counted-vmcnt dbuf ---
// 528 blocks (~2 generations/CU vs 8.1 at 128^2), half the L2 staging traffic,
// XCD-bijective swizzle (528 = 66x8) for A-panel L2 reuse. Per-64B-slice LDS
// layout + XOR swizzle byte-identical to the proven r0 scheme (conflict-0).
__global__ __launch_bounds__(1024, 4) void k_main(
    const unsigned char* __restrict__ Xb, const float* __restrict__ sqv,
    const float* __restrict__ coef, float* __restrict__ bpart) {
  // XCD-aware bijective swizzle: consecutive work-ids land on one XCD
  int wg = (int)blockIdx.x;
  int b = (wg % 8) * (NTRI2 / 8) + wg / 8;
  // triangular decode: tile b -> (bi, bj), bi <= bj   (NB2 = 32)
  int bi = (int)((2.f * NB2 + 1.f - sqrtf((float)((2 * NB2 + 1) * (2 * NB2 + 1) - 8 * b))) * 0.5f);
  if (bi < 0) bi = 0;
  if (bi > NB2 - 1) bi = NB2 - 1;
  while ((bi + 1) * (2 * NB2 - bi) / 2 <= b) ++bi;
  while (bi * (2 * NB2 - bi + 1) / 2 > b) --bi;
  int bj = bi + (b - bi * (2 * NB2 - bi + 1) / 2);

  __shared__ __align__(16) unsigned char ldsA[2][256 * 64];  // 32 KB (2 ko-slices)
  __shared__ __align__(16) unsigned char ldsB[2][256 * 64];  // 32 KB
  __shared__ float sqA[256], sqB[256];
  __shared__ float redw[16];

  int t = threadIdx.x, l = t & 63, w = t >> 6;     // 16 waves
  int lr = l & 31, half = l >> 5;
  int waveRow = w >> 2, waveCol = w & 3;           // 4x4 wave grid, 64x64 each

  const unsigned char* arow = Xb + (size_t)bi * 256 * D;
  const unsigned char* brow = Xb + (size_t)bj * 256 * D;

  // sq rows via per-lane loads + LDS store (compiler orders these vmem itself)
  if (t < 256)      sqA[t] = sqv[bi * 256 + t];
  else if (t < 512) sqB[t - 256] = sqv[bj * 256 + (t - 256)];
  float A4 = coef[0];                       // s_load (lgkmcnt), not vmcnt
  asm volatile("" :: "s"(A4));
  asm volatile("" ::: "memory");            // sq vmem retired before STAGE issue

  // STAGE(k): exactly 2 vmem per thread (1 A + 1 B), 64B K-slice k -> buf[k&1]
  auto STAGE = [&](int k) {
    int row = t >> 2;
    int kb = (t & 3) ^ (row & 3) ^ ((row >> 2) & 3);
    int goff = row * D + k * 64 + kb * 16;
    gload16(arow + goff, &ldsA[k & 1][w * 1024]);
    gload16(brow + goff, &ldsB[k & 1][w * 1024]);
  };

  STAGE(0);
  STAGE(1);                                 // 4 vmem outstanding

  f32x16 acc[2][2] = {};
  int cLo = 2 * half, cHi = 2 * half + 1;   // lane's logical 16B chunks

  #pragma unroll
  for (int ko = 0; ko < 4; ++ko) {
    if (ko < 3)      asm volatile("s_waitcnt vmcnt(2)" ::: "memory");  // slice ko done
    else             asm volatile("s_waitcnt vmcnt(0)" ::: "memory");
    __builtin_amdgcn_s_barrier();           // all waves' slice-ko data visible
    const unsigned char* lA = &ldsA[ko & 1][0];
    const unsigned char* lB = &ldsB[ko & 1][0];
    i32x8 aF[2];
    #pragma unroll
    for (int rb = 0; rb < 2; ++rb) {
      int rowA = waveRow * 64 + rb * 32 + lr;
      int sw = (rowA & 3) ^ ((rowA >> 2) & 3);
      i32x4 lo = *(const i32x4*)&lA[rowA * 64 + (cLo ^ sw) * 16];
      i32x4 hi = *(const i32x4*)&lA[rowA * 64 + (cHi ^ sw) * 16];
      aF[rb] = (i32x8){lo.x, lo.y, lo.z, lo.w, hi.x, hi.y, hi.z, hi.w};
    }
    #pragma unroll
    for (int cb = 0; cb < 2; ++cb) {
      int rowB = waveCol * 64 + cb * 32 + lr;
      int sw = (rowB & 3) ^ ((rowB >> 2) & 3);
      i32x4 lo = *(const i32x4*)&lB[rowB * 64 + (cLo ^ sw) * 16];
      i32x4 hi = *(const i32x4*)&lB[rowB * 64 + (cHi ^ sw) * 16];
      i32x8 bF = (i32x8){lo.x, lo.y, lo.z, lo.w, hi.x, hi.y, hi.z, hi.w};
      #pragma unroll
      for (int rb = 0; rb < 2; ++rb)
        acc[rb][cb] = __builtin_amdgcn_mfma_scale_f32_32x32x64_f8f6f4(
            aF[rb], bF, acc[rb][cb], 0, 0, 0, 127, 0, 127);
    }
    if (ko < 2) {
      // all waves done READING buf[ko&1] before refilling it
      asm volatile("s_waitcnt lgkmcnt(0)" ::: "memory");
      __builtin_amdgcn_s_barrier();
      STAGE(ko + 2);
    }
  }

  // Packed epilogue: tt = 2A4*dot - A4*sqi - A4*sqj ; e = exp2(tt)
  // sum5 = e+e^2+e^4+e^8+e^16 ; C/D layout: col=lane&31, row=(r&3)+8*(r>>2)+4*(lane>>5)
  float c2A4 = 2.f * A4, nA4 = -A4;
  f32x2 lsum2 = {0.f, 0.f};
  bool diag = (bi == bj);
  #pragma unroll
  for (int cb = 0; cb < 2; ++cb) {
    int jj = waveCol * 64 + cb * 32 + lr;
    float bjv = nA4 * sqB[jj];
    #pragma unroll
    for (int rb = 0; rb < 2; ++rb) {
      #pragma unroll
      for (int r = 0; r < 16; r += 2) {
        int ii = waveRow * 64 + rb * 32 + (r & 3) + 8 * (r >> 2) + 4 * half;
        f32x2 dot2 = {acc[rb][cb][r], acc[rb][cb][r + 1]};
        f32x2 sq2 = {sqA[ii], sqA[ii + 1]};
        f32x2 tt = c2A4 * dot2 + (nA4 * sq2 + bjv);
        f32x2 e;
        e.x = __builtin_amdgcn_exp2f(tt.x);
        e.y = __builtin_amdgcn_exp2f(tt.y);
        f32x2 e2 = e * e, e4 = e2 * e2, e8 = e4 * e4, e16 = e8 * e8;
        f32x2 kern = ((e + e2) + (e4 + e8)) + e16;
        if (diag) {                          // block-uniform branch
          if (ii == jj) kern.x = 0.f;
          if (ii + 1 == jj) kern.y = 0.f;
        }
        lsum2 += kern;
      }
    }
  }
  float lsum = lsum2.x + lsum2.y;
  for (int o = 32; o > 0; o >>= 1) lsum += __shfl_down(lsum, o, 64);
  if (l == 0) redw[w] = lsum;
  __syncthreads();
  if (t == 0) {
    float tot = 0.f;
    #pragma unroll
    for (int i = 0; i < 16; ++i) tot += redw[i];
    float wgt = diag ? 1.f : 2.f;                                 // symmetry weight
    float sgn = ((bi < HALF_B2) == (bj < HALF_B2)) ? 1.f : -1.f;  // s_i * s_j
    bpart[b] = tot * wgt * sgn;
  }
}

// ---- K4: final fp64 reduction + analytic diagonal + mean ----
__global__ void k_final(const float* __restrict__ bpart, float* __restrict__ out) {
  __shared__ double red[256];
  int t = threadIdx.x;
  double s = 0.0;
  #pragma unroll
  for (int k = 0; k < 3; ++k) {
    int idx = k * 256 + t;
    if (idx < NTRI2) s += (double)bpart[idx];
  }
  red[t] = s;
  __syncthreads();
  for (int st = 128; st > 0; st >>= 1) {
    if (t < st) red[t] += red[t + st];
    __syncthreads();
  }
  if (t == 0) {
    double total = red[0] + 5.0 * (double)N_TOT;  // diagonal: K_ii = 5, sign +1
    out[0] = (float)(total / ((double)NS * (double)NS));
  }
}

extern "C" void kernel_launch(void* const* d_in, const int* in_sizes, int n_in,
                              void* d_out, int out_size, void* d_ws, size_t ws_size,
                              hipStream_t stream) {
  const float* src = (const float*)d_in[0];
  const float* tgt = (const float*)d_in[1];
  float* out = (float*)d_out;
  char* ws = (char*)d_ws;
  unsigned char* Xb = (unsigned char*)ws;                       // 2 MB fp8 row-major
  float* sqv  = (float*)(ws + (4u << 20));                      // 32 KB row sq-norms
  float* pm   = (float*)(ws + (4u << 20) + (32u << 10));        // 256 KB col partials
  float* wsqp = (float*)(ws + (4u << 20) + (288u << 10));       // 1 KB sq partials
  float* coef = (float*)(ws + (4u << 20) + (289u << 10));       // 4 B
  float* bpart = (float*)(ws + (4u << 20) + (290u << 10));      // 2.1 KB tile partials

  hipLaunchKernelGGL(k_prep, dim3(256), dim3(256), 0, stream, src, tgt, Xb, sqv, pm, wsqp);
  hipLaunchKernelGGL(k_bw, dim3(1), dim3(1024), 0, stream, pm, wsqp, coef);
  hipLaunchKernelGGL(k_main, dim3(NTRI2), dim3(1024), 0, stream, Xb, sqv, coef, bpart);
  hipLaunchKernelGGL(k_final, dim3(1), dim3(256), 0, stream, bpart, out);
}

// Round 8
// 96.497 us; speedup vs baseline: 1.1234x; 1.0384x over previous
//
#include <hip/hip_runtime.h>

#define N_TOT 8192
#define NS 4096
#define D 256                 // elements per row; fp8 => also bytes per row
#define NBW 128               // 8192/64 row-groups of 64
#define NTRIW (NBW*(NBW+1)/2) // 8256 upper-triangle 64x64 wave-tiles
#define HALF_W 64

typedef float f32x16 __attribute__((ext_vector_type(16)));
typedef float f32x2 __attribute__((ext_vector_type(2)));
typedef int i32x4 __attribute__((ext_vector_type(4)));
typedef int i32x8 __attribute__((ext_vector_type(8)));

// ---- K1: fp8 convert (fragment-ordered store) + row sq-norms + col partials.
// Xf layout: [group g = row>>5][ko = K-slice][lane l = half*32 + (row&31)][32B]
//   lane l's 32 B = bytes [half*32, half*32+32) of row (g*32+(l&31))'s 64-B
//   K-slice ko  — exactly the mfma_scale_32x32x64 A/B fragment for lane l.
// So each wave-fragment is a contiguous 2 KB span: minimum-line L1/L2 reads.
__global__ void k_prep(const float* __restrict__ src, const float* __restrict__ tgt,
                       unsigned char* __restrict__ Xf, float* __restrict__ sqv,
                       float* __restrict__ pm, float* __restrict__ wsqp) {
  __shared__ float colacc[256];
  __shared__ float wred[4];
  int t = threadIdx.x, l = t & 63, w = t >> 6;
  colacc[t] = 0.f;
  __syncthreads();
  int base = blockIdx.x * 32;
  float c0 = 0.f, c1 = 0.f, c2 = 0.f, c3 = 0.f;
  float wsq = 0.f;
  int ko = l >> 4;                 // this lane's 4B lands in K-slice (4l)>>6
  int half = (l >> 3) & 1;         // ((4l)&63)>>5
  int off4 = l & 7;                // int offset within the 32-B lane slot
  #pragma unroll
  for (int r = 0; r < 8; ++r) {
    int row = base + w * 8 + r;
    const float* p = (row < NS) ? (src + (size_t)row * D) : (tgt + (size_t)(row - NS) * D);
    float4 v = ((const float4*)p)[l];
    int pk = __builtin_amdgcn_cvt_pk_fp8_f32(v.x, v.y, 0, false);   // bytes 0,1
    pk = __builtin_amdgcn_cvt_pk_fp8_f32(v.z, v.w, pk, true);       // bytes 2,3
    int g = row >> 5, rl = row & 31;
    ((int*)Xf)[g * 2048 + ko * 512 + (half * 32 + rl) * 8 + off4] = pk;
    c0 += v.x; c1 += v.y; c2 += v.z; c3 += v.w;
    float s = fmaf(v.x, v.x, fmaf(v.y, v.y, fmaf(v.z, v.z, v.w * v.w)));
    for (int o = 32; o > 0; o >>= 1) s += __shfl_down(s, o, 64);
    if (l == 0) { sqv[row] = s; wsq += s; }
  }
  atomicAdd(&colacc[4 * l + 0], c0);
  atomicAdd(&colacc[4 * l + 1], c1);
  atomicAdd(&colacc[4 * l + 2], c2);
  atomicAdd(&colacc[4 * l + 3], c3);
  if (l == 0) wred[w] = wsq;
  __syncthreads();
  pm[blockIdx.x * 256 + t] = colacc[t];
  if (t == 0) wsqp[blockIdx.x] = (wred[0] + wred[1]) + (wred[2] + wred[3]);
}

// ---- K2: reduce partials, finalize bandwidth in fp64 (r5 exact) ----
__global__ __launch_bounds__(1024) void k_bw(const float* __restrict__ pm,
                                             const float* __restrict__ wsqp,
                                             float* __restrict__ coef) {
  __shared__ float csh[1024];
  __shared__ double red[256];
  int t = threadIdx.x;
  int col = t & 255, q = t >> 8;          // q = 0..3: which 64-block slice
  float cs = 0.f;
  #pragma unroll
  for (int b = 0; b < 64; ++b) cs += pm[(q * 64 + b) * 256 + col];
  csh[t] = cs;
  __syncthreads();
  if (t < 256) {
    float c = (csh[t] + csh[t + 256]) + (csh[t + 512] + csh[t + 768]);
    red[t] = (double)c * (double)c;
  }
  __syncthreads();
  for (int s = 128; s > 0; s >>= 1) {
    if (t < s) red[t] += red[t + s];
    __syncthreads();
  }
  double msq = red[0];
  __syncthreads();
  if (t < 256) red[t] = (double)wsqp[t];
  __syncthreads();
  for (int s = 128; s > 0; s >>= 1) {
    if (t < s) red[t] += red[t + s];
    __syncthreads();
  }
  if (t == 0) {
    double Sv = red[0];
    double n = (double)N_TOT;
    double sumL2 = 2.0 * n * Sv - 2.0 * msq;
    double bw = sumL2 / (n * n - n) / 4.0;        // / KERNEL_MUL**(KERNEL_NUM//2)
    double c4 = 1.0 / (bw * 16.0 + 1e-6);         // widest kernel (k=4)
    coef[0] = (float)(c4 * 1.4426950408889634);   // * log2(e) for exp2
  }
}

// ---- K3: one independent wave per 64x64 tile. ZERO LDS, ZERO barriers. ----
// Xf is L2-resident (2 MB/XCD); fragments load straight to VGPRs from the
// pre-swizzled layout (contiguous 2 KB per fragment). 2-deep compiler-
// scheduled pipeline. Per-acc K-order identical to r0 -> same MFMA bits.
__global__ __launch_bounds__(256) void k_main(
    const unsigned char* __restrict__ Xf, const float* __restrict__ sqv,
    const float* __restrict__ coef, float* __restrict__ bpart) {
  int t = threadIdx.x, l = t & 63, w = t >> 6;
  int lr = l & 31, half = l >> 5;
  int b = blockIdx.x * 4 + w;               // this wave's tile
  // triangular decode: b -> (bi, bj), bi <= bj   (NBW = 128)
  int bi = (int)((2.f * NBW + 1.f - sqrtf((float)((2 * NBW + 1) * (2 * NBW + 1) - 8 * b))) * 0.5f);
  if (bi < 0) bi = 0;
  if (bi > NBW - 1) bi = NBW - 1;
  while ((bi + 1) * (2 * NBW - bi) / 2 <= b) ++bi;
  while (bi * (2 * NBW - bi + 1) / 2 > b) --bi;
  int bj = bi + (b - bi * (2 * NBW - bi + 1) / 2);

  const unsigned char* pa = Xf + (size_t)(2 * bi) * 8192 + (size_t)l * 32;
  const unsigned char* pb = Xf + (size_t)(2 * bj) * 8192 + (size_t)l * 32;
  float A4 = coef[0];

  auto LD = [&](const unsigned char* base, int rb, int ko) -> i32x8 {
    const unsigned char* p = base + rb * 8192 + ko * 2048;
    i32x4 lo = *(const i32x4*)p;
    i32x4 hi = *(const i32x4*)(p + 16);
    return (i32x8){lo.x, lo.y, lo.z, lo.w, hi.x, hi.y, hi.z, hi.w};
  };

  i32x8 fa[2][2], fb[2][2];                 // [buf][rb/cb]
  #pragma unroll
  for (int rb = 0; rb < 2; ++rb) {
    fa[0][rb] = LD(pa, rb, 0); fb[0][rb] = LD(pb, rb, 0);
    fa[1][rb] = LD(pa, rb, 1); fb[1][rb] = LD(pb, rb, 1);
  }

  f32x16 acc[2][2] = {};
  #pragma unroll
  for (int ko = 0; ko < 4; ++ko) {
    const int cur = ko & 1;
    #pragma unroll
    for (int cb = 0; cb < 2; ++cb)
      #pragma unroll
      for (int rb = 0; rb < 2; ++rb)
        acc[rb][cb] = __builtin_amdgcn_mfma_scale_f32_32x32x64_f8f6f4(
            fa[cur][rb], fb[cur][cb], acc[rb][cb], 0, 0, 0, 127, 0, 127);
    if (ko < 2) {
      #pragma unroll
      for (int rb = 0; rb < 2; ++rb) {
        fa[cur][rb] = LD(pa, rb, ko + 2);
        fb[cur][rb] = LD(pb, rb, ko + 2);
      }
    }
  }

  // Packed epilogue (identical arithmetic; sq from L2-hot sqv, not LDS)
  const float* sqa = sqv + bi * 64;
  const float* sqb = sqv + bj * 64;
  float c2A4 = 2.f * A4, nA4 = -A4;
  f32x2 lsum2 = {0.f, 0.f};
  bool diag = (bi == bj);
  #pragma unroll
  for (int cb = 0; cb < 2; ++cb) {
    int jj = cb * 32 + lr;
    float bjv = nA4 * sqb[jj];
    #pragma unroll
    for (int rb = 0; rb < 2; ++rb) {
      #pragma unroll
      for (int r = 0; r < 16; r += 2) {
        int ii = rb * 32 + (r & 3) + 8 * (r >> 2) + 4 * half;
        f32x2 dot2 = {acc[rb][cb][r], acc[rb][cb][r + 1]};
        f32x2 sq2 = *(const f32x2*)(sqa + ii);   // ii even -> 8B aligned
        f32x2 tt = c2A4 * dot2 + (nA4 * sq2 + bjv);
        f32x2 e;
        e.x = __builtin_amdgcn_exp2f(tt.x);
        e.y = __builtin_amdgcn_exp2f(tt.y);
        f32x2 e2 = e * e, e4 = e2 * e2, e8 = e4 * e4, e16 = e8 * e8;
        f32x2 kern = ((e + e2) + (e4 + e8)) + e16;
        if (diag) {                          // wave-uniform branch
          if (ii == jj) kern.x = 0.f;
          if (ii + 1 == jj) kern.y = 0.f;
        }
        lsum2 += kern;
      }
    }
  }
  float lsum = lsum2.x + lsum2.y;
  for (int o = 32; o > 0; o >>= 1) lsum += __shfl_down(lsum, o, 64);
  if (l == 0) {
    float wgt = diag ? 1.f : 2.f;                                 // symmetry weight
    float sgn = ((bi < HALF_W) == (bj < HALF_W)) ? 1.f : -1.f;    // s_i * s_j
    bpart[b] = lsum * wgt * sgn;
  }
}

// ---- K4: final fp64 reduction + analytic diagonal + mean ----
__global__ void k_final(const float* __restrict__ bpart, float* __restrict__ out) {
  __shared__ double red[256];
  int t = threadIdx.x;
  double s = 0.0;
  #pragma unroll
  for (int k = 0; k < 33; ++k) {
    int idx = k * 256 + t;
    if (idx < NTRIW) s += (double)bpart[idx];
  }
  red[t] = s;
  __syncthreads();
  for (int st = 128; st > 0; st >>= 1) {
    if (t < st) red[t] += red[t + st];
    __syncthreads();
  }
  if (t == 0) {
    double total = red[0] + 5.0 * (double)N_TOT;  // diagonal: K_ii = 5, sign +1
    out[0] = (float)(total / ((double)NS * (double)NS));
  }
}

extern "C" void kernel_launch(void* const* d_in, const int* in_sizes, int n_in,
                              void* d_out, int out_size, void* d_ws, size_t ws_size,
                              hipStream_t stream) {
  const float* src = (const float*)d_in[0];
  const float* tgt = (const float*)d_in[1];
  float* out = (float*)d_out;
  char* ws = (char*)d_ws;
  unsigned char* Xf = (unsigned char*)ws;                       // 2 MB fp8 fragment-order
  float* sqv  = (float*)(ws + (4u << 20));                      // 32 KB row sq-norms
  float* pm   = (float*)(ws + (4u << 20) + (32u << 10));        // 256 KB col partials
  float* wsqp = (float*)(ws + (4u << 20) + (288u << 10));       // 1 KB sq partials
  float* coef = (float*)(ws + (4u << 20) + (289u << 10));       // 4 B
  float* bpart = (float*)(ws + (4u << 20) + (290u << 10));      // 33 KB tile partials

  hipLaunchKernelGGL(k_prep, dim3(256), dim3(256), 0, stream, src, tgt, Xf, sqv, pm, wsqp);
  hipLaunchKernelGGL(k_bw, dim3(1), dim3(1024), 0, stream, pm, wsqp, coef);
  hipLaunchKernelGGL(k_main, dim3(NTRIW / 4), dim3(256), 0, stream, Xf, sqv, coef, bpart);
  hipLaunchKernelGGL(k_final, dim3(1), dim3(256), 0, stream, bpart, out);
}

// Round 9
// 96.094 us; speedup vs baseline: 1.1281x; 1.0042x over previous
//
#include <hip/hip_runtime.h>

#define N_TOT 8192
#define NS 4096
#define D 256                 // elements per row; fp8 => also bytes per row
#define NB 64                 // 8192/128 tiles per dim
#define NTRI (NB*(NB+1)/2)    // 2080 upper-triangle tiles
#define HALF_B 32

typedef float f32x16 __attribute__((ext_vector_type(16)));
typedef float f32x2 __attribute__((ext_vector_type(2)));
typedef int i32x4 __attribute__((ext_vector_type(4)));
typedef int i32x8 __attribute__((ext_vector_type(8)));

__device__ __forceinline__ void gload16(const void* g, void* l) {
  __builtin_amdgcn_global_load_lds(
      (const __attribute__((address_space(1))) unsigned int*)g,
      (__attribute__((address_space(3))) unsigned int*)l,
      16, 0, 0);
}

// ---- K1: one pass: fp8 e4m3 convert + row sq-norms + per-block partials ----
// r9: 512 threads (8 waves, 2 blocks/CU) for 2x latency hiding on the
// per-row shuffle-reduce chains; work split 4 rows/wave (was 8).
__global__ __launch_bounds__(512) void k_prep(
    const float* __restrict__ src, const float* __restrict__ tgt,
    unsigned char* __restrict__ Xb, float* __restrict__ sqv,
    float* __restrict__ pm, float* __restrict__ wsqp) {
  __shared__ float colacc[256];
  __shared__ float wred[8];
  int t = threadIdx.x, l = t & 63, w = t >> 6;   // 8 waves
  if (t < 256) colacc[t] = 0.f;
  __syncthreads();
  int base = blockIdx.x * 32;
  float c0 = 0.f, c1 = 0.f, c2 = 0.f, c3 = 0.f;
  float wsq = 0.f;
  #pragma unroll
  for (int r = 0; r < 4; ++r) {
    int row = base + w * 4 + r;
    const float* p = (row < NS) ? (src + (size_t)row * D) : (tgt + (size_t)(row - NS) * D);
    float4 v = ((const float4*)p)[l];
    int pk = __builtin_amdgcn_cvt_pk_fp8_f32(v.x, v.y, 0, false);   // bytes 0,1
    pk = __builtin_amdgcn_cvt_pk_fp8_f32(v.z, v.w, pk, true);       // bytes 2,3
    ((int*)(Xb + (size_t)row * D))[l] = pk;                         // 4 B/lane coalesced
    c0 += v.x; c1 += v.y; c2 += v.z; c3 += v.w;
    float s = fmaf(v.x, v.x, fmaf(v.y, v.y, fmaf(v.z, v.z, v.w * v.w)));
    for (int o = 32; o > 0; o >>= 1) s += __shfl_down(s, o, 64);
    if (l == 0) { sqv[row] = s; wsq += s; }
  }
  atomicAdd(&colacc[4 * l + 0], c0);
  atomicAdd(&colacc[4 * l + 1], c1);
  atomicAdd(&colacc[4 * l + 2], c2);
  atomicAdd(&colacc[4 * l + 3], c3);
  if (l == 0) wred[w] = wsq;
  __syncthreads();
  if (t < 256) pm[blockIdx.x * 256 + t] = colacc[t];
  if (t == 0) {
    wsqp[blockIdx.x] = ((wred[0] + wred[1]) + (wred[2] + wred[3])) +
                       ((wred[4] + wred[5]) + (wred[6] + wred[7]));
  }
}

// ---- K2: reduce partials, finalize bandwidth in fp64 (r5 exact) ----
__global__ __launch_bounds__(1024) void k_bw(const float* __restrict__ pm,
                                             const float* __restrict__ wsqp,
                                             float* __restrict__ coef) {
  __shared__ float csh[1024];
  __shared__ double red[256];
  int t = threadIdx.x;
  int col = t & 255, q = t >> 8;          // q = 0..3: which 64-block slice
  float cs = 0.f;
  #pragma unroll
  for (int b = 0; b < 64; ++b) cs += pm[(q * 64 + b) * 256 + col];
  csh[t] = cs;
  __syncthreads();
  if (t < 256) {
    float c = (csh[t] + csh[t + 256]) + (csh[t + 512] + csh[t + 768]);
    red[t] = (double)c * (double)c;
  }
  __syncthreads();
  for (int s = 128; s > 0; s >>= 1) {
    if (t < s) red[t] += red[t + s];
    __syncthreads();
  }
  double msq = red[0];
  __syncthreads();
  if (t < 256) red[t] = (double)wsqp[t];
  __syncthreads();
  for (int s = 128; s > 0; s >>= 1) {
    if (t < s) red[t] += red[t + s];
    __syncthreads();
  }
  if (t == 0) {
    double Sv = red[0];
    double n = (double)N_TOT;
    double sumL2 = 2.0 * n * Sv - 2.0 * msq;
    double bw = sumL2 / (n * n - n) / 4.0;        // / KERNEL_MUL**(KERNEL_NUM//2)
    double c4 = 1.0 / (bw * 16.0 + 1e-6);         // widest kernel (k=4)
    coef[0] = (float)(c4 * 1.4426950408889634);   // * log2(e) for exp2
  }
}

// ---- K3: 128x128 upper-tri tiles, MX-scaled fp8 32x32x64 MFMA (unit scales) ----
// r0-exact — best measured across 6 structural variants (r0/r2/r4/r7/r8).
__global__ __launch_bounds__(256) void k_main(
    const unsigned char* __restrict__ Xb, const float* __restrict__ sqv,
    const float* __restrict__ coef, float* __restrict__ bpart) {
  // triangular decode: block b -> (bi, bj), bi <= bj
  int b = blockIdx.x;
  int bi = (int)((2.f * NB + 1.f - sqrtf((float)((2 * NB + 1) * (2 * NB + 1) - 8 * b))) * 0.5f);
  if (bi < 0) bi = 0;
  if (bi > NB - 1) bi = NB - 1;
  while ((bi + 1) * (2 * NB - bi) / 2 <= b) ++bi;
  while (bi * (2 * NB - bi + 1) / 2 > b) --bi;
  int bj = bi + (b - bi * (2 * NB - bi + 1) / 2);

  __shared__ unsigned char ldsA[128 * 64];   // 8 KB  [row][64B stage-slice]
  __shared__ unsigned char ldsB[128 * 64];   // 8 KB
  __shared__ float sqA[128], sqB[128];
  __shared__ float redw[4];

  int t = threadIdx.x, l = t & 63, w = t >> 6;
  int lr = l & 31, half = l >> 5;
  int waveRow = w >> 1, waveCol = w & 1;

  if (t < 128) sqA[t] = sqv[bi * 128 + t];
  else         sqB[t - 128] = sqv[bj * 128 + (t - 128)];
  float A4 = coef[0];

  const unsigned char* arow = Xb + (size_t)bi * 128 * D;
  const unsigned char* brow = Xb + (size_t)bj * 128 * D;

  f32x16 acc[2][2] = {};
  int cLo = 2 * half, cHi = 2 * half + 1;   // lane's logical 16B chunks

  for (int ko = 0; ko < 4; ++ko) {
    if (ko) __syncthreads();
    int kOff = ko * 64;                     // byte offset in row
    #pragma unroll
    for (int p = 0; p < 2; ++p) {           // 512 16B segs per matrix
      int seg = p * 256 + t;
      int row = seg >> 2;
      int kb = (seg & 3) ^ (row & 3) ^ ((row >> 2) & 3);
      int goff = row * D + kOff + kb * 16;
      gload16(arow + goff, &ldsA[(p * 256 + w * 64) * 16]);
      gload16(brow + goff, &ldsB[(p * 256 + w * 64) * 16]);
    }
    __syncthreads();
    i32x8 aF[2];
    #pragma unroll
    for (int rb = 0; rb < 2; ++rb) {
      int rowA = waveRow * 64 + rb * 32 + lr;
      int sw = (rowA & 3) ^ ((rowA >> 2) & 3);
      i32x4 lo = *(const i32x4*)&ldsA[rowA * 64 + (cLo ^ sw) * 16];
      i32x4 hi = *(const i32x4*)&ldsA[rowA * 64 + (cHi ^ sw) * 16];
      aF[rb] = (i32x8){lo.x, lo.y, lo.z, lo.w, hi.x, hi.y, hi.z, hi.w};
    }
    #pragma unroll
    for (int cb = 0; cb < 2; ++cb) {
      int rowB = waveCol * 64 + cb * 32 + lr;
      int sw = (rowB & 3) ^ ((rowB >> 2) & 3);
      i32x4 lo = *(const i32x4*)&ldsB[rowB * 64 + (cLo ^ sw) * 16];
      i32x4 hi = *(const i32x4*)&ldsB[rowB * 64 + (cHi ^ sw) * 16];
      i32x8 bF = (i32x8){lo.x, lo.y, lo.z, lo.w, hi.x, hi.y, hi.z, hi.w};
      #pragma unroll
      for (int rb = 0; rb < 2; ++rb)
        acc[rb][cb] = __builtin_amdgcn_mfma_scale_f32_32x32x64_f8f6f4(
            aF[rb], bF, acc[rb][cb], 0, 0, 0, 127, 0, 127);
    }
  }

  // Packed epilogue: tt = 2A4*dot - A4*sqi - A4*sqj ; e = exp2(tt)
  // sum5 = e+e^2+e^4+e^8+e^16 (exp-squaring; bw_k = bw*2^k exactly)
  // C/D layout (shape-determined, dtype-independent): col=lane&31,
  // row=(r&3)+8*(r>>2)+4*(lane>>5)
  float c2A4 = 2.f * A4, nA4 = -A4;
  f32x2 lsum2 = {0.f, 0.f};
  bool diag = (bi == bj);
  #pragma unroll
  for (int cb = 0; cb < 2; ++cb) {
    int jj = waveCol * 64 + cb * 32 + lr;
    float bjv = nA4 * sqB[jj];
    #pragma unroll
    for (int rb = 0; rb < 2; ++rb) {
      #pragma unroll
      for (int r = 0; r < 16; r += 2) {
        int ii = waveRow * 64 + rb * 32 + (r & 3) + 8 * (r >> 2) + 4 * half;
        f32x2 dot2 = {acc[rb][cb][r], acc[rb][cb][r + 1]};
        f32x2 sq2 = {sqA[ii], sqA[ii + 1]};
        f32x2 tt = c2A4 * dot2 + (nA4 * sq2 + bjv);
        f32x2 e;
        e.x = __builtin_amdgcn_exp2f(tt.x);
        e.y = __builtin_amdgcn_exp2f(tt.y);
        f32x2 e2 = e * e, e4 = e2 * e2, e8 = e4 * e4, e16 = e8 * e8;
        f32x2 kern = ((e + e2) + (e4 + e8)) + e16;
        if (diag) {                          // block-uniform branch
          if (ii == jj) kern.x = 0.f;
          if (ii + 1 == jj) kern.y = 0.f;
        }
        lsum2 += kern;
      }
    }
  }
  float lsum = lsum2.x + lsum2.y;
  for (int o = 32; o > 0; o >>= 1) lsum += __shfl_down(lsum, o, 64);
  if (l == 0) redw[w] = lsum;
  __syncthreads();
  if (t == 0) {
    float tot = (redw[0] + redw[1]) + (redw[2] + redw[3]);
    float wgt = diag ? 1.f : 2.f;                               // symmetry weight
    float sgn = ((bi < HALF_B) == (bj < HALF_B)) ? 1.f : -1.f;  // s_i * s_j
    bpart[b] = tot * wgt * sgn;
  }
}

// ---- K4: final fp64 reduction + analytic diagonal + mean ----
__global__ void k_final(const float* __restrict__ bpart, float* __restrict__ out) {
  __shared__ double red[256];
  int t = threadIdx.x;
  double s = 0.0;
  #pragma unroll
  for (int k = 0; k < 9; ++k) {
    int idx = k * 256 + t;
    if (idx < NTRI) s += (double)bpart[idx];
  }
  red[t] = s;
  __syncthreads();
  for (int st = 128; st > 0; st >>= 1) {
    if (t < st) red[t] += red[t + st];
    __syncthreads();
  }
  if (t == 0) {
    double total = red[0] + 5.0 * (double)N_TOT;  // diagonal: K_ii = 5, sign +1
    out[0] = (float)(total / ((double)NS * (double)NS));
  }
}

extern "C" void kernel_launch(void* const* d_in, const int* in_sizes, int n_in,
                              void* d_out, int out_size, void* d_ws, size_t ws_size,
                              hipStream_t stream) {
  const float* src = (const float*)d_in[0];
  const float* tgt = (const float*)d_in[1];
  float* out = (float*)d_out;
  char* ws = (char*)d_ws;
  unsigned char* Xb = (unsigned char*)ws;                       // 2 MB fp8 row-major
  float* sqv  = (float*)(ws + (4u << 20));                      // 32 KB row sq-norms
  float* pm   = (float*)(ws + (4u << 20) + (32u << 10));        // 256 KB col partials
  float* wsqp = (float*)(ws + (4u << 20) + (288u << 10));       // 1 KB sq partials
  float* coef = (float*)(ws + (4u << 20) + (289u << 10));       // 4 B
  float* bpart = (float*)(ws + (4u << 20) + (290u << 10));      // 8.3 KB tile partials

  hipLaunchKernelGGL(k_prep, dim3(256), dim3(512), 0, stream, src, tgt, Xb, sqv, pm, wsqp);
  hipLaunchKernelGGL(k_bw, dim3(1), dim3(1024), 0, stream, pm, wsqp, coef);
  hipLaunchKernelGGL(k_main, dim3(NTRI), dim3(256), 0, stream, Xb, sqv, coef, bpart);
  hipLaunchKernelGGL(k_final, dim3(1), dim3(256), 0, stream, bpart, out);
}